// Round 16
// baseline (45513.651 us; speedup 1.0000x reference)
//
#include <hip/hip_runtime.h>
#include <math.h>

// ---------------------------------------------------------------------------
// BiLSTM-CRF inference.
//   lstm:    NEW 64-WG variant (32/dir, 32 units/WG): halves the per-step
//            straggler pool (consumer waits on max over 32 producers, not 64;
//            WG-count curve: 256WG=3.1us, 128WG=2.22us/step -> sample 64WG).
//            Weights: 256 bf16/thread streamed from L2, issued before the
//            sentinel poll (1 MB/XCD — half of r13's thrashing 2 MB).
//   sgemm:   bf16 MFMA 128x128/BK=32 (r14, verified).
//   viterbi: 48-lane parallel forward (r15, verified).
// ---------------------------------------------------------------------------

#define T_LEN 4096
#define NTAG 12
#define START_TAG 10
#define STOP_TAG 11
#define NEG_VAL (-10000.0f)

typedef int   v4i __attribute__((ext_vector_type(4)));
typedef float v4f __attribute__((ext_vector_type(4)));
typedef short sh8 __attribute__((ext_vector_type(8)));
typedef float f32x4 __attribute__((ext_vector_type(4)));

// workspace layout in floats
#define OF_EMB  0UL                                 // emb_bf [4096][544] ushort
#define OF_W    (OF_EMB + 4096UL * 544UL)           // w_bf   [8192][544] ushort
#define OF_BIAS (OF_W + 8192UL * 544UL)             // bias   [8192] f32
#define OF_PRE  (OF_BIAS + 8192UL)                  // pre    [4096][8192] f32
#define OF_HF   (OF_PRE + 4096UL * 8192UL)          // hf     [4097][1024]
#define OF_HB   (OF_HF + 4097UL * 1024UL)           // hb     [4097][1024]
#define OF_FEAT (OF_HB + 4097UL * 1024UL)           // feats  [4096][12]
// wpk4 (bf16 w_hh for lstm64, 16 MB) aliases OF_EMB.. (emb/w_bf dead after sgemm)

__device__ __forceinline__ float fsig(float v) {
    return 1.0f / (1.0f + __expf(-v));
}
__device__ __forceinline__ float ftanhf(float v) {
    float a = fabsf(v);
    float e = __expf(-2.0f * a);
    float r = (1.0f - e) / (1.0f + e);
    return copysignf(r, v);
}
__device__ __forceinline__ unsigned f2bf(float x) {  // RNE fp32->bf16
    unsigned u = __float_as_uint(x);
    u += 0x7fffu + ((u >> 16) & 1u);
    return u >> 16;
}
__device__ __forceinline__ float bflo(unsigned d) { return __uint_as_float(d << 16); }
__device__ __forceinline__ float bfhi(unsigned d) { return __uint_as_float(d & 0xffff0000u); }

// ---------------------------------------------------------------------------
// pack w_ih -> bf16 [8192][544] (K padded with zeros) + fused bias
__global__ void prep_w_kernel(const float* __restrict__ wf, const float* __restrict__ wb,
                              const float* __restrict__ bif, const float* __restrict__ bhf,
                              const float* __restrict__ bib, const float* __restrict__ bhb,
                              unsigned short* __restrict__ wbf, float* __restrict__ bias) {
    int n = blockIdx.x;  // 0..8191
    const float* src = (n < 4096) ? (wf + (size_t)n * 537) : (wb + (size_t)(n - 4096) * 537);
    unsigned short* dst = wbf + (size_t)n * 544;
    for (int k = threadIdx.x; k < 544; k += blockDim.x)
        dst[k] = (k < 537) ? (unsigned short)f2bf(src[k]) : (unsigned short)0;
    if (threadIdx.x == 0)
        bias[n] = (n < 4096) ? (bif[n] + bhf[n]) : (bib[n - 4096] + bhb[n - 4096]);
}

// ---------------------------------------------------------------------------
// pack w_hh -> bf16, lstm64 layout: wpk4[((b*8+wv)*64+lane)*32 + q] covers
// row R=64*(wv>>2)+lane (gate g=R>>5, unit u=R&31 -> w row g*1024+widx*32+u),
// cols 256*(wv&3) + 8q..+7 (dword e: col pair 8q+2e, 8q+2e+1).
__global__ __launch_bounds__(512) void prep_whh64_kernel(const float* __restrict__ wf,
                                                         const float* __restrict__ wb,
                                                         uint4* __restrict__ wpk4) {
    int b = blockIdx.x, tid = threadIdx.x;   // b = dir*32 + widx
    int dir = b >> 5, widx = b & 31;
    int wv = tid >> 6, lane = tid & 63;
    int ch = wv & 3, rb = wv >> 2;
    int R = 64 * rb + lane;
    int g = R >> 5, u = R & 31;
    const float* row = (dir ? wb : wf) + (size_t)(g * 1024 + widx * 32 + u) * 1024 + 256 * ch;
    uint4* dst = wpk4 + ((size_t)(b * 8 + wv) * 64 + lane) * 32;
    #pragma unroll
    for (int q = 0; q < 32; ++q) {
        const float* c8 = row + 8 * q;
        unsigned d0 = f2bf(c8[0]) | (f2bf(c8[1]) << 16);
        unsigned d1 = f2bf(c8[2]) | (f2bf(c8[3]) << 16);
        unsigned d2 = f2bf(c8[4]) | (f2bf(c8[5]) << 16);
        unsigned d3 = f2bf(c8[6]) | (f2bf(c8[7]) << 16);
        dst[q] = make_uint4(d0, d1, d2, d3);
    }
}

// ---------------------------------------------------------------------------
// char CNN + word-emb gather -> emb_bf [4096][544] bf16
__global__ void charcnn_kernel(const int* __restrict__ sentence, const int* __restrict__ chars,
                               const float* __restrict__ cemb, const float* __restrict__ cw,
                               const float* __restrict__ cb, const float* __restrict__ wemb,
                               unsigned short* __restrict__ emb) {
    int t = blockIdx.x, tid = threadIdx.x;
    __shared__ float ce[500];   // [20][25]
    __shared__ float yv[550];   // [25][22]
    for (int i = tid; i < 500; i += 256) {
        int c = chars[t * 20 + i / 25];
        ce[i] = cemb[c * 25 + i % 25];
    }
    __syncthreads();
    for (int i = tid; i < 550; i += 256) {
        int o = i / 22, p = i % 22;
        float v = cb[o];
        #pragma unroll
        for (int kh = 0; kh < 3; ++kh) {
            int ir = p - 2 + kh;  // zero padding of 2 on top/bottom
            if (ir >= 0 && ir < 20) {
                const float* crow = ce + ir * 25;
                const float* wrow = cw + o * 75 + kh * 25;
                #pragma unroll
                for (int kw = 0; kw < 25; ++kw) v = fmaf(crow[kw], wrow[kw], v);
            }
        }
        yv[o * 22 + p] = v;
    }
    __syncthreads();
    unsigned short* erow = emb + (size_t)t * 544;
    int sidx = sentence[t];
    if (tid < 128) {  // word embedding: 128 x float4 -> 128 x (4 bf16)
        float4 v = ((const float4*)(wemb + (size_t)sidx * 512))[tid];
        uint2 pk;
        pk.x = f2bf(v.x) | (f2bf(v.y) << 16);
        pk.y = f2bf(v.z) | (f2bf(v.w) << 16);
        ((uint2*)erow)[tid] = pk;
    }
    if (tid >= 128 && tid < 153) {  // char features (25)
        int o = tid - 128;
        const float* yo = yv + o * 22;
        float m = yo[0];
        #pragma unroll
        for (int p = 1; p < 22; ++p) m = fmaxf(m, yo[p]);
        erow[512 + o] = (unsigned short)f2bf(m);
    }
    if (tid >= 160 && tid < 167) erow[537 + (tid - 160)] = 0;  // K padding
}

// ---------------------------------------------------------------------------
// bf16 MFMA GEMM: pre[4096][8192] = emb_bf @ w_bf^T + bias (fp32 out).
__global__ __launch_bounds__(256) void sgemm_kernel(const unsigned short* __restrict__ A,
                                                    const unsigned short* __restrict__ B,
                                                    const float* __restrict__ bias,
                                                    float* __restrict__ C) {
    __shared__ unsigned short As[128 * 40];
    __shared__ unsigned short Bs[128 * 40];
    const int tid = threadIdx.x;
    const int wv = tid >> 6, lane = tid & 63;
    const int l15 = lane & 15, l4 = lane >> 4;
    const int m0 = blockIdx.y * 128, n0 = blockIdx.x * 128;
    const int srow = tid >> 2, sslot = tid & 3;   // staging: 4 thr/row, 16B each

    f32x4 acc[2][8];
    #pragma unroll
    for (int mt = 0; mt < 2; ++mt)
        #pragma unroll
        for (int nt = 0; nt < 8; ++nt) acc[mt][nt] = (f32x4){0.f, 0.f, 0.f, 0.f};

    for (int kt = 0; kt < 17; ++kt) {
        const int kof = kt * 32 + sslot * 8;
        uint4 a0 = *(const uint4*)(A + (size_t)(m0 + srow) * 544 + kof);
        uint4 a1 = *(const uint4*)(A + (size_t)(m0 + 64 + srow) * 544 + kof);
        uint4 b0 = *(const uint4*)(B + (size_t)(n0 + srow) * 544 + kof);
        uint4 b1 = *(const uint4*)(B + (size_t)(n0 + 64 + srow) * 544 + kof);
        __syncthreads();
        *(uint4*)&As[srow * 40 + sslot * 8] = a0;
        *(uint4*)&As[(64 + srow) * 40 + sslot * 8] = a1;
        *(uint4*)&Bs[srow * 40 + sslot * 8] = b0;
        *(uint4*)&Bs[(64 + srow) * 40 + sslot * 8] = b1;
        __syncthreads();
        sh8 bfr[8];
        #pragma unroll
        for (int nt = 0; nt < 8; ++nt)
            bfr[nt] = *(const sh8*)&Bs[(16 * nt + l15) * 40 + l4 * 8];
        #pragma unroll
        for (int mt = 0; mt < 2; ++mt) {
            sh8 afr = *(const sh8*)&As[(32 * wv + 16 * mt + l15) * 40 + l4 * 8];
            #pragma unroll
            for (int nt = 0; nt < 8; ++nt)
                acc[mt][nt] = __builtin_amdgcn_mfma_f32_16x16x32_bf16(
                    afr, bfr[nt], acc[mt][nt], 0, 0, 0);
        }
    }
    #pragma unroll
    for (int mt = 0; mt < 2; ++mt) {
        int mrow = m0 + 32 * wv + 16 * mt + l4 * 4;
        #pragma unroll
        for (int nt = 0; nt < 8; ++nt) {
            int col = n0 + 16 * nt + l15;
            float bz = bias[col];
            #pragma unroll
            for (int r = 0; r < 4; ++r)
                C[(size_t)(mrow + r) * 8192 + col] = acc[mt][nt][r] + bz;
        }
    }
}

// ---------------------------------------------------------------------------
// Persistent bidirectional LSTM, 64 WGs x 512 thr (32/dir, 32 units/WG).
// Wave wv: col-quarter ch=wv&3 (cols 256ch..+255), row-block rb=wv>>2;
// lane = local row offset: R = 64rb+lane (gate g=R>>5, unit u=R&31).
// Per step: issue 32 bf16 weight dwordx4 (plain, L2) BEFORE the poll; each
// lane polls h quad 64ch+lane (sc1, data-as-flag; first vmcnt(0) drains the
// weight stream under the producer wait); dot via 64 shfl-broadcast quads;
// LDS partials + 1 barrier; wave-0 lanes 0..31 do gates (one unit each) and
// lanes 0..7 publish 8 quads (sc1).
__global__ __launch_bounds__(512, 2) void lstm_kernel(const uint4* __restrict__ wpk4,
                                                      const float* __restrict__ pre,
                                                      float* __restrict__ hfbuf,
                                                      float* __restrict__ hbbuf) {
    const int tid = threadIdx.x;
    const int dir = blockIdx.x >> 5;
    const int widx = blockIdx.x & 31;
    const int j0 = widx * 32;
    const int wv = tid >> 6, lane = tid & 63;
    const int ch = wv & 3;
    __shared__ __align__(16) float partials[2][8][64];  // [parity][wave][lane]

    const uint4* wq = wpk4 + ((size_t)(blockIdx.x * 8 + wv) * 64 + lane) * 32;
    float* hbuf = dir ? hbbuf : hfbuf;
    const int dirofs = dir ? 4096 : 0;
    float c = 0.f;

    for (int s = 0; s < T_LEN; ++s) {
        const int t = dir ? (T_LEN - 1 - s) : s;
        const int rdslot = dir ? (t + 1) : t;
        const int wrslot = dir ? t : (t + 1);
        const int p = s & 1;

        // (1) issue this step's 32 weight quad loads (plain; L2-resident —
        // 1 MB/XCD working set) — they stream under the h-wait.
        v4i wd[32];
        #pragma unroll
        for (int q = 0; q < 32; ++q)
            asm volatile("global_load_dwordx4 %0, %1, off"
                         : "=v"(wd[q]) : "v"(wq + q));

        // pre-activation inputs for this lane's unit (wave 0 lanes 0..31)
        float pg0 = 0.f, pg1 = 0.f, pg2 = 0.f, pg3 = 0.f;
        if (tid < 32) {
            const float* pb = pre + (size_t)t * 8192 + dirofs + j0 + tid;
            pg0 = pb[0];
            pg1 = pb[1024];
            pg2 = pb[2048];
            pg3 = pb[3072];
        }

        // (2) poll own quad of h_prev (quad 64ch+lane; data IS the flag).
        const float* hp = hbuf + ((size_t)rdslot << 10) + ((64 * ch + lane) << 2);
        v4i hq;
        asm volatile("global_load_dwordx4 %0, %1, off sc1\n\ts_waitcnt vmcnt(0)"
                     : "=v"(hq) : "v"(hp));
        while (true) {
            bool miss = (hq.x == -1 || hq.y == -1 || hq.z == -1 || hq.w == -1);
            if (!__any(miss)) break;
            __builtin_amdgcn_s_sleep(1);
            if (miss) {
                asm volatile("global_load_dwordx4 %0, %1, off sc1\n\ts_waitcnt vmcnt(0)"
                             : "=v"(hq) : "v"(hp));
            }
        }

        // (3) dot: h quad k (cols 256ch+4k..+3) lives in lane k of this wave;
        // weights: wd[k>>1], k even -> (.x,.y), k odd -> (.z,.w).
        float acc = 0.f;
        #pragma unroll
        for (int k = 0; k < 64; ++k) {
            float hx = __shfl(__int_as_float(hq.x), k);
            float hy = __shfl(__int_as_float(hq.y), k);
            float hz = __shfl(__int_as_float(hq.z), k);
            float hw = __shfl(__int_as_float(hq.w), k);
            unsigned dA = (k & 1) ? (unsigned)wd[k >> 1].z : (unsigned)wd[k >> 1].x;
            unsigned dB = (k & 1) ? (unsigned)wd[k >> 1].w : (unsigned)wd[k >> 1].y;
            acc = fmaf(bflo(dA), hx, acc);
            acc = fmaf(bfhi(dA), hy, acc);
            acc = fmaf(bflo(dB), hz, acc);
            acc = fmaf(bfhi(dB), hw, acc);
        }
        partials[p][wv][lane] = acc;
        __syncthreads();  // (4) the ONE barrier per step

        // (5) gates + publish: wave 0 lanes 0..31, one unit each
        if (tid < 32) {
            // row for gate g: R=g*32+tid -> wave (g>>1)*4+ch', lane (g&1)*32+tid
            float d0 = partials[p][0][tid] + partials[p][1][tid]
                     + partials[p][2][tid] + partials[p][3][tid];          // g=0 (rb0 lo)
            float d1 = partials[p][0][32 + tid] + partials[p][1][32 + tid]
                     + partials[p][2][32 + tid] + partials[p][3][32 + tid]; // g=1 (rb0 hi)
            float d2 = partials[p][4][tid] + partials[p][5][tid]
                     + partials[p][6][tid] + partials[p][7][tid];          // g=2 (rb1 lo)
            float d3 = partials[p][4][32 + tid] + partials[p][5][32 + tid]
                     + partials[p][6][32 + tid] + partials[p][7][32 + tid]; // g=3 (rb1 hi)
            float ig = fsig(pg0 + d0);
            float fg = fsig(pg1 + d1);
            float gt = ftanhf(pg2 + d2);
            float og = fsig(pg3 + d3);
            c = fg * c + ig * gt;
            float h = og * ftanhf(c);
            // pack: lanes 0..7 build quad qi for units 4qi..4qi+3
            v4f hv;
            hv.x = __shfl(h, (tid << 2) & 31);
            hv.y = __shfl(h, ((tid << 2) + 1) & 31);
            hv.z = __shfl(h, ((tid << 2) + 2) & 31);
            hv.w = __shfl(h, ((tid << 2) + 3) & 31);
            if (tid < 8) {
                float* hp2 = hbuf + ((size_t)wrslot << 10) + j0 + (tid << 2);
                asm volatile("global_store_dwordx4 %0, %1, off sc1"
                             :: "v"(hp2), "v"(hv));
            }
        }
    }
}

// ---------------------------------------------------------------------------
// feats[t][tag] = [hf[t] | hb[t]] . w_tag[tag] + b_tag[tag]  (float4 + swizzle)
__global__ __launch_bounds__(192) void tagproj_kernel(const float* __restrict__ hfbuf,
                                                      const float* __restrict__ hbbuf,
                                                      const float* __restrict__ wtag,
                                                      const float* __restrict__ btag,
                                                      float* __restrict__ feats) {
    int t = blockIdx.x, tid = threadIdx.x;
    __shared__ float4 hs4[512];   // 2048 floats, block-XOR swizzled
    for (int i = tid; i < 512; i += 192) {
        float4 q = (i < 256)
            ? ((const float4*)(hfbuf + ((size_t)(t + 1) << 10)))[i]
            : ((const float4*)(hbbuf + ((size_t)t << 10)))[i - 256];
        hs4[i ^ ((i >> 5) & 7)] = q;
    }
    __syncthreads();
    int tag = tid >> 4, sl = tid & 15;  // 12 tags x 16 slices of 128 cols
    const float4* wrow4 = (const float4*)(wtag + (size_t)tag * 2048 + (sl << 7));
    float a = 0.f;
    #pragma unroll
    for (int m = 0; m < 32; ++m) {
        float4 h4 = hs4[(sl << 5) + (m ^ (sl & 7))];
        float4 w4 = wrow4[m];
        a = fmaf(h4.x, w4.x, a);
        a = fmaf(h4.y, w4.y, a);
        a = fmaf(h4.z, w4.z, a);
        a = fmaf(h4.w, w4.w, a);
    }
    a += __shfl_xor(a, 1);
    a += __shfl_xor(a, 2);
    a += __shfl_xor(a, 4);
    a += __shfl_xor(a, 8);
    if (sl == 0) feats[t * 12 + tag] = a + btag[tag];
}

// ---------------------------------------------------------------------------
// CRF forward + backtrace, single wave, 48-lane parallel step (r15, verified).
__global__ __launch_bounds__(64) void viterbi_kernel(const float* __restrict__ feats,
                                                     const float* __restrict__ trans,
                                                     float* __restrict__ out) {
    const int tid = threadIdx.x;     // 0..63
    const int q = tid >> 4;          // from-chunk 0..3 (from = 3q..3q+2)
    const int to = tid & 15;         // tag column (valid < 12)
    const int toc = (to < 12) ? to : 11;
    __shared__ float fbuf[256 * 12];
    __shared__ unsigned char bp[4096 * 12];

    const float trf0 = trans[(3 * q + 0) * 12 + toc];
    const float trf1 = trans[(3 * q + 1) * 12 + toc];
    const float trf2 = trans[(3 * q + 2) * 12 + toc];
    const float tstop = (tid < 12) ? trans[tid * 12 + STOP_TAG] : 0.f;
    float alpha = (tid == START_TAG) ? 0.f : NEG_VAL;  // meaningful lanes 0..11

    for (int ck = 0; ck < 16; ++ck) {
        __syncthreads();
        for (int i = tid; i < 3072; i += 64) fbuf[i] = feats[ck * 3072 + i];
        __syncthreads();
        for (int tt = 0; tt < 256; ++tt) {
            float feat = fbuf[tt * 12 + toc];
            float af0 = __shfl(alpha, 3 * q + 0);
            float af1 = __shfl(alpha, 3 * q + 1);
            float af2 = __shfl(alpha, 3 * q + 2);
            float s0 = (af0 + feat) + trf0;
            float s1 = (af1 + feat) + trf1;
            float s2 = (af2 + feat) + trf2;
            float m = s0; int bi = 3 * q;
            if (s1 > m) { m = s1; bi = 3 * q + 1; }
            if (s2 > m) { m = s2; bi = 3 * q + 2; }
            float mo = __shfl_xor(m, 16);
            int io = __shfl_xor(bi, 16);
            if (!((m > mo) || (m == mo && bi < io))) { m = mo; bi = io; }
            mo = __shfl_xor(m, 32);
            io = __shfl_xor(bi, 32);
            if (!((m > mo) || (m == mo && bi < io))) { m = mo; bi = io; }
            float e = __expf(s0 - m) + __expf(s1 - m) + __expf(s2 - m);
            e += __shfl_xor(e, 16);
            e += __shfl_xor(e, 32);
            alpha = __logf(e) + m;
            if (q == 0 && to < 12)
                bp[(ck * 256 + tt) * 12 + to] = (unsigned char)bi;
        }
    }
    __syncthreads();
    if (tid < 12) {
        float fin = alpha + tstop;
        float m = -INFINITY;
        int bl = 0;
        #pragma unroll
        for (int f = 0; f < 12; ++f) {
            float vf = __shfl(fin, f);
            if (vf > m) { m = vf; bl = f; }
        }
        float sum = 0.f;
        #pragma unroll
        for (int f = 0; f < 12; ++f) {
            float vf = __shfl(fin, f);
            sum += __expf(vf - m);
        }
        float score = __logf(sum) + m;
        if (tid == 0) {
            out[0] = score;            // output 0: score
            out[4096] = (float)bl;     // path[4095]
        }
        int cur = bl;
        for (int tt = 4095; tt >= 1; --tt) {
            int bv = (int)bp[tt * 12 + tid];
            cur = __shfl(bv, cur);     // path[tt-1] = bp[tt][path[tt]]
            if (tid == 0) out[tt] = (float)cur;
        }
    }
}

// ---------------------------------------------------------------------------
extern "C" void kernel_launch(void* const* d_in, const int* in_sizes, int n_in,
                              void* d_out, int out_size, void* d_ws, size_t ws_size,
                              hipStream_t stream) {
    (void)in_sizes; (void)n_in; (void)out_size; (void)ws_size;
    const int* sentence = (const int*)d_in[0];
    const int* chars = (const int*)d_in[1];
    // d_in[2] (caps) is unused by the reference forward
    const float* cemb = (const float*)d_in[3];
    const float* cw = (const float*)d_in[4];
    const float* cb = (const float*)d_in[5];
    const float* wemb = (const float*)d_in[6];
    const float* w_ih_f = (const float*)d_in[7];
    const float* w_hh_f = (const float*)d_in[8];
    const float* b_ih_f = (const float*)d_in[9];
    const float* b_hh_f = (const float*)d_in[10];
    const float* w_ih_b = (const float*)d_in[11];
    const float* w_hh_b = (const float*)d_in[12];
    const float* b_ih_b = (const float*)d_in[13];
    const float* b_hh_b = (const float*)d_in[14];
    const float* wtag = (const float*)d_in[15];
    const float* btag = (const float*)d_in[16];
    const float* trans = (const float*)d_in[17];

    float* ws = (float*)d_ws;
    unsigned short* emb_bf = (unsigned short*)(ws + OF_EMB);
    unsigned short* w_bf = (unsigned short*)(ws + OF_W);
    float* bias = ws + OF_BIAS;
    float* pre = ws + OF_PRE;
    float* hf = ws + OF_HF;
    float* hb = ws + OF_HB;
    float* feats = ws + OF_FEAT;
    uint4* wpk4 = (uint4*)(ws + OF_EMB);  // 16 MB; emb/w_bf dead after sgemm

    // sentinel-fill h buffers, then zero the two initial-state slots
    (void)hipMemsetAsync(hf, 0xFF, 4097UL * 1024UL * 4UL, stream);
    (void)hipMemsetAsync(hb, 0xFF, 4097UL * 1024UL * 4UL, stream);
    (void)hipMemsetAsync(hf, 0x00, 1024UL * 4UL, stream);                    // hf slot 0
    (void)hipMemsetAsync(hb + 4096UL * 1024UL, 0x00, 1024UL * 4UL, stream);  // hb slot T

    hipLaunchKernelGGL(prep_w_kernel, dim3(8192), dim3(256), 0, stream,
                       w_ih_f, w_ih_b, b_ih_f, b_hh_f, b_ih_b, b_hh_b, w_bf, bias);
    hipLaunchKernelGGL(charcnn_kernel, dim3(4096), dim3(256), 0, stream,
                       sentence, chars, cemb, cw, cb, wemb, emb_bf);
    hipLaunchKernelGGL(sgemm_kernel, dim3(64, 32), dim3(256), 0, stream,
                       emb_bf, w_bf, bias, pre);
    // emb/w_bf dead; pack lstm64 bf16 weights into their space
    hipLaunchKernelGGL(prep_whh64_kernel, dim3(64), dim3(512), 0, stream,
                       w_hh_f, w_hh_b, wpk4);
    hipLaunchKernelGGL(lstm_kernel, dim3(64), dim3(512), 0, stream,
                       wpk4, pre, hf, hb);
    hipLaunchKernelGGL(tagproj_kernel, dim3(4096), dim3(192), 0, stream,
                       hf, hb, wtag, btag, feats);
    hipLaunchKernelGGL(viterbi_kernel, dim3(1), dim3(64), 0, stream,
                       feats, trans, (float*)d_out);
}

// Round 17
// 10720.839 us; speedup vs baseline: 4.2453x; 4.2453x over previous
//
#include <hip/hip_runtime.h>
#include <math.h>

// ---------------------------------------------------------------------------
// BiLSTM-CRF inference — FINAL configuration (round-15, best: 10.71 ms).
//   lstm:    128 WGs x 512 thr, 16 units/WG, fp32 weights + asm ties,
//            wave-0 32-lane sentinel-poll (data-as-flag), 8-iter shfl dot,
//            one barrier/step. Measured optimum of: WG count {256,128,64},
//            sync {dword-poll, quad-poll, flags, data-as-flag}, weight
//            residency {cap, no-clobber, ties, low-pressure, L2-stream},
//            hop count {4,2}. 2.22 us/step = serial-chain floor.
//   sgemm:   bf16 MFMA 128x128/BK=32 (r14).
//   viterbi: 48-lane parallel forward + shuffle backtrace (r15).
// ---------------------------------------------------------------------------

#define T_LEN 4096
#define NTAG 12
#define START_TAG 10
#define STOP_TAG 11
#define NEG_VAL (-10000.0f)

typedef int   v4i __attribute__((ext_vector_type(4)));
typedef float v4f __attribute__((ext_vector_type(4)));
typedef short sh8 __attribute__((ext_vector_type(8)));
typedef float f32x4 __attribute__((ext_vector_type(4)));

// workspace layout in floats
#define OF_EMB  0UL                                 // emb_bf [4096][544] ushort
#define OF_W    (OF_EMB + 4096UL * 544UL)           // w_bf   [8192][544] ushort
#define OF_BIAS (OF_W + 8192UL * 544UL)             // bias   [8192] f32
#define OF_PRE  (OF_BIAS + 8192UL)                  // pre    [4096][8192] f32
#define OF_HF   (OF_PRE + 4096UL * 8192UL)          // hf     [4097][1024]
#define OF_HB   (OF_HF + 4097UL * 1024UL)           // hb     [4097][1024]
#define OF_FEAT (OF_HB + 4097UL * 1024UL)           // feats  [4096][12]

__device__ __forceinline__ float fsig(float v) {
    return 1.0f / (1.0f + __expf(-v));
}
__device__ __forceinline__ float ftanhf(float v) {
    float a = fabsf(v);
    float e = __expf(-2.0f * a);
    float r = (1.0f - e) / (1.0f + e);
    return copysignf(r, v);
}
__device__ __forceinline__ unsigned f2bf(float x) {  // RNE fp32->bf16
    unsigned u = __float_as_uint(x);
    u += 0x7fffu + ((u >> 16) & 1u);
    return u >> 16;
}

// ---------------------------------------------------------------------------
// pack w_ih -> bf16 [8192][544] (K padded with zeros) + fused bias
__global__ void prep_w_kernel(const float* __restrict__ wf, const float* __restrict__ wb,
                              const float* __restrict__ bif, const float* __restrict__ bhf,
                              const float* __restrict__ bib, const float* __restrict__ bhb,
                              unsigned short* __restrict__ wbf, float* __restrict__ bias) {
    int n = blockIdx.x;  // 0..8191
    const float* src = (n < 4096) ? (wf + (size_t)n * 537) : (wb + (size_t)(n - 4096) * 537);
    unsigned short* dst = wbf + (size_t)n * 544;
    for (int k = threadIdx.x; k < 544; k += blockDim.x)
        dst[k] = (k < 537) ? (unsigned short)f2bf(src[k]) : (unsigned short)0;
    if (threadIdx.x == 0)
        bias[n] = (n < 4096) ? (bif[n] + bhf[n]) : (bib[n - 4096] + bhb[n - 4096]);
}

// ---------------------------------------------------------------------------
// char CNN + word-emb gather -> emb_bf [4096][544] bf16
__global__ void charcnn_kernel(const int* __restrict__ sentence, const int* __restrict__ chars,
                               const float* __restrict__ cemb, const float* __restrict__ cw,
                               const float* __restrict__ cb, const float* __restrict__ wemb,
                               unsigned short* __restrict__ emb) {
    int t = blockIdx.x, tid = threadIdx.x;
    __shared__ float ce[500];   // [20][25]
    __shared__ float yv[550];   // [25][22]
    for (int i = tid; i < 500; i += 256) {
        int c = chars[t * 20 + i / 25];
        ce[i] = cemb[c * 25 + i % 25];
    }
    __syncthreads();
    for (int i = tid; i < 550; i += 256) {
        int o = i / 22, p = i % 22;
        float v = cb[o];
        #pragma unroll
        for (int kh = 0; kh < 3; ++kh) {
            int ir = p - 2 + kh;  // zero padding of 2 on top/bottom
            if (ir >= 0 && ir < 20) {
                const float* crow = ce + ir * 25;
                const float* wrow = cw + o * 75 + kh * 25;
                #pragma unroll
                for (int kw = 0; kw < 25; ++kw) v = fmaf(crow[kw], wrow[kw], v);
            }
        }
        yv[o * 22 + p] = v;
    }
    __syncthreads();
    unsigned short* erow = emb + (size_t)t * 544;
    int sidx = sentence[t];
    if (tid < 128) {  // word embedding: 128 x float4 -> 128 x (4 bf16)
        float4 v = ((const float4*)(wemb + (size_t)sidx * 512))[tid];
        uint2 pk;
        pk.x = f2bf(v.x) | (f2bf(v.y) << 16);
        pk.y = f2bf(v.z) | (f2bf(v.w) << 16);
        ((uint2*)erow)[tid] = pk;
    }
    if (tid >= 128 && tid < 153) {  // char features (25)
        int o = tid - 128;
        const float* yo = yv + o * 22;
        float m = yo[0];
        #pragma unroll
        for (int p = 1; p < 22; ++p) m = fmaxf(m, yo[p]);
        erow[512 + o] = (unsigned short)f2bf(m);
    }
    if (tid >= 160 && tid < 167) erow[537 + (tid - 160)] = 0;  // K padding
}

// ---------------------------------------------------------------------------
// bf16 MFMA GEMM: pre[4096][8192] = emb_bf @ w_bf^T + bias (fp32 out).
__global__ __launch_bounds__(256) void sgemm_kernel(const unsigned short* __restrict__ A,
                                                    const unsigned short* __restrict__ B,
                                                    const float* __restrict__ bias,
                                                    float* __restrict__ C) {
    __shared__ unsigned short As[128 * 40];
    __shared__ unsigned short Bs[128 * 40];
    const int tid = threadIdx.x;
    const int wv = tid >> 6, lane = tid & 63;
    const int l15 = lane & 15, l4 = lane >> 4;
    const int m0 = blockIdx.y * 128, n0 = blockIdx.x * 128;
    const int srow = tid >> 2, sslot = tid & 3;   // staging: 4 thr/row, 16B each

    f32x4 acc[2][8];
    #pragma unroll
    for (int mt = 0; mt < 2; ++mt)
        #pragma unroll
        for (int nt = 0; nt < 8; ++nt) acc[mt][nt] = (f32x4){0.f, 0.f, 0.f, 0.f};

    for (int kt = 0; kt < 17; ++kt) {
        const int kof = kt * 32 + sslot * 8;
        uint4 a0 = *(const uint4*)(A + (size_t)(m0 + srow) * 544 + kof);
        uint4 a1 = *(const uint4*)(A + (size_t)(m0 + 64 + srow) * 544 + kof);
        uint4 b0 = *(const uint4*)(B + (size_t)(n0 + srow) * 544 + kof);
        uint4 b1 = *(const uint4*)(B + (size_t)(n0 + 64 + srow) * 544 + kof);
        __syncthreads();
        *(uint4*)&As[srow * 40 + sslot * 8] = a0;
        *(uint4*)&As[(64 + srow) * 40 + sslot * 8] = a1;
        *(uint4*)&Bs[srow * 40 + sslot * 8] = b0;
        *(uint4*)&Bs[(64 + srow) * 40 + sslot * 8] = b1;
        __syncthreads();
        sh8 bfr[8];
        #pragma unroll
        for (int nt = 0; nt < 8; ++nt)
            bfr[nt] = *(const sh8*)&Bs[(16 * nt + l15) * 40 + l4 * 8];
        #pragma unroll
        for (int mt = 0; mt < 2; ++mt) {
            sh8 afr = *(const sh8*)&As[(32 * wv + 16 * mt + l15) * 40 + l4 * 8];
            #pragma unroll
            for (int nt = 0; nt < 8; ++nt)
                acc[mt][nt] = __builtin_amdgcn_mfma_f32_16x16x32_bf16(
                    afr, bfr[nt], acc[mt][nt], 0, 0, 0);
        }
    }
    #pragma unroll
    for (int mt = 0; mt < 2; ++mt) {
        int mrow = m0 + 32 * wv + 16 * mt + l4 * 4;
        #pragma unroll
        for (int nt = 0; nt < 8; ++nt) {
            int col = n0 + 16 * nt + l15;
            float bz = bias[col];
            #pragma unroll
            for (int r = 0; r < 4; ++r)
                C[(size_t)(mrow + r) * 8192 + col] = acc[mt][nt][r] + bz;
        }
    }
}

// ---------------------------------------------------------------------------
// Persistent bidirectional LSTM — round-11 kernel VERBATIM (best: 9.08 ms).
__global__ __launch_bounds__(512, 2) void lstm_kernel(const float* __restrict__ whhf,
                                                      const float* __restrict__ whhb,
                                                      const float* __restrict__ pre,
                                                      float* __restrict__ hfbuf,
                                                      float* __restrict__ hbbuf) {
    const int tid = threadIdx.x;
    const int dir = blockIdx.x >> 6;
    const int widx = blockIdx.x & 63;
    const int j0 = widx * 16;
    const int c32 = tid >> 4;       // col-group: cols 32*c32 .. +31
    const int r4 = tid & 15;        // row-group: local rows 4*r4 .. +3
    const int lane = tid & 63;
    const int wv = tid >> 6;
    const bool pol = (r4 < 8);      // polling lanes (32/wave, dedup slice)
    __shared__ __align__(16) float partials[2][8][64];  // [parity][wave][row]

    // weights: local row R = 4*r4+i -> gate g=R>>4, unit jj=R&15
    v4f w[4][8];
    #pragma unroll
    for (int i = 0; i < 4; ++i) {
        int R = 4 * r4 + i;
        const v4f* wsrc = (const v4f*)((dir ? whhb : whhf) +
            (size_t)(((R >> 4) << 10) + j0 + (R & 15)) * 1024 + c32 * 32);
        #pragma unroll
        for (int m = 0; m < 8; ++m) w[i][m] = wsrc[m];
    }
    #pragma unroll
    for (int i = 0; i < 4; ++i)
        #pragma unroll
        for (int m = 0; m < 8; ++m)
            asm volatile("" : "+v"(w[i][m]));

    float* hbuf = dir ? hbbuf : hfbuf;
    const int dirofs = dir ? 4096 : 0;
    float c = 0.f;

    for (int s = 0; s < T_LEN; ++s) {
        const int t = dir ? (T_LEN - 1 - s) : s;
        const int rdslot = dir ? (t + 1) : t;
        const int wrslot = dir ? t : (t + 1);
        const int p = s & 1;

        float preg = 0.f;
        if (tid < 64)
            preg = pre[(size_t)t * 8192 + dirofs + ((lane & 3) << 10) + j0 + (lane >> 2)];

        const float* hp = hbuf + ((size_t)rdslot << 10) + c32 * 32 + r4 * 4;
        v4i hq;
        hq.x = 0; hq.y = 0; hq.z = 0; hq.w = 0;
        if (pol) {
            asm volatile("global_load_dwordx4 %0, %1, off sc1\n\ts_waitcnt vmcnt(0)"
                         : "=v"(hq) : "v"(hp));
        }
        while (true) {
            bool miss = pol && (hq.x == -1 || hq.y == -1 || hq.z == -1 || hq.w == -1);
            if (!__any(miss)) break;
            __builtin_amdgcn_s_sleep(1);
            if (miss) {
                asm volatile("global_load_dwordx4 %0, %1, off sc1\n\ts_waitcnt vmcnt(0)"
                             : "=v"(hq) : "v"(hp));
            }
        }

        float a0 = 0.f, a1 = 0.f, a2 = 0.f, a3 = 0.f;
        #pragma unroll
        for (int m = 0; m < 8; ++m) {
            int src = (lane & 48) + m;
            float hx = __shfl(__int_as_float(hq.x), src);
            float hy = __shfl(__int_as_float(hq.y), src);
            float hz = __shfl(__int_as_float(hq.z), src);
            float hw = __shfl(__int_as_float(hq.w), src);
            a0 = fmaf(w[0][m].x, hx, a0); a0 = fmaf(w[0][m].y, hy, a0);
            a0 = fmaf(w[0][m].z, hz, a0); a0 = fmaf(w[0][m].w, hw, a0);
            a1 = fmaf(w[1][m].x, hx, a1); a1 = fmaf(w[1][m].y, hy, a1);
            a1 = fmaf(w[1][m].z, hz, a1); a1 = fmaf(w[1][m].w, hw, a1);
            a2 = fmaf(w[2][m].x, hx, a2); a2 = fmaf(w[2][m].y, hy, a2);
            a2 = fmaf(w[2][m].z, hz, a2); a2 = fmaf(w[2][m].w, hw, a2);
            a3 = fmaf(w[3][m].x, hx, a3); a3 = fmaf(w[3][m].y, hy, a3);
            a3 = fmaf(w[3][m].z, hz, a3); a3 = fmaf(w[3][m].w, hw, a3);
        }
        a0 += __shfl_xor(a0, 16); a0 += __shfl_xor(a0, 32);
        a1 += __shfl_xor(a1, 16); a1 += __shfl_xor(a1, 32);
        a2 += __shfl_xor(a2, 16); a2 += __shfl_xor(a2, 32);
        a3 += __shfl_xor(a3, 16); a3 += __shfl_xor(a3, 32);
        if ((lane >> 4) == 0)
            *(float4*)&partials[p][wv][r4 << 2] = make_float4(a0, a1, a2, a3);
        __syncthreads();  // the ONE barrier per step

        if (tid < 64) {
            int rql = ((lane & 3) << 4) + (lane >> 2);  // local row g*16+jj
            float dsum = 0.f;
            #pragma unroll
            for (int q = 0; q < 8; ++q) dsum += partials[p][q][rql];
            float val = preg + dsum;
            float act = ((lane & 3) == 2) ? ftanhf(val) : fsig(val);
            int base = lane & ~3;
            float iv = __shfl(act, base);
            float fv = __shfl(act, base + 1);
            float gv = __shfl(act, base + 2);
            float ov = __shfl(act, base + 3);
            c = fv * c + iv * gv;
            float h = ov * ftanhf(c);
            v4f hv;
            hv.x = __shfl(h, (lane << 4) & 63);
            hv.y = __shfl(h, ((lane << 4) + 4) & 63);
            hv.z = __shfl(h, ((lane << 4) + 8) & 63);
            hv.w = __shfl(h, ((lane << 4) + 12) & 63);
            if (lane < 4) {
                float* hp2 = hbuf + ((size_t)wrslot << 10) + j0 + (lane << 2);
                asm volatile("global_store_dwordx4 %0, %1, off sc1"
                             :: "v"(hp2), "v"(hv));
            }
        }
    }
}

// ---------------------------------------------------------------------------
// feats[t][tag] = [hf[t] | hb[t]] . w_tag[tag] + b_tag[tag]  (float4 + swizzle)
__global__ __launch_bounds__(192) void tagproj_kernel(const float* __restrict__ hfbuf,
                                                      const float* __restrict__ hbbuf,
                                                      const float* __restrict__ wtag,
                                                      const float* __restrict__ btag,
                                                      float* __restrict__ feats) {
    int t = blockIdx.x, tid = threadIdx.x;
    __shared__ float4 hs4[512];   // 2048 floats, block-XOR swizzled
    for (int i = tid; i < 512; i += 192) {
        float4 q = (i < 256)
            ? ((const float4*)(hfbuf + ((size_t)(t + 1) << 10)))[i]
            : ((const float4*)(hbbuf + ((size_t)t << 10)))[i - 256];
        hs4[i ^ ((i >> 5) & 7)] = q;
    }
    __syncthreads();
    int tag = tid >> 4, sl = tid & 15;  // 12 tags x 16 slices of 128 cols
    const float4* wrow4 = (const float4*)(wtag + (size_t)tag * 2048 + (sl << 7));
    float a = 0.f;
    #pragma unroll
    for (int m = 0; m < 32; ++m) {
        float4 h4 = hs4[(sl << 5) + (m ^ (sl & 7))];
        float4 w4 = wrow4[m];
        a = fmaf(h4.x, w4.x, a);
        a = fmaf(h4.y, w4.y, a);
        a = fmaf(h4.z, w4.z, a);
        a = fmaf(h4.w, w4.w, a);
    }
    a += __shfl_xor(a, 1);
    a += __shfl_xor(a, 2);
    a += __shfl_xor(a, 4);
    a += __shfl_xor(a, 8);
    if (sl == 0) feats[t * 12 + tag] = a + btag[tag];
}

// ---------------------------------------------------------------------------
// CRF forward + backtrace, single wave, 48-lane parallel step (r15, verified).
__global__ __launch_bounds__(64) void viterbi_kernel(const float* __restrict__ feats,
                                                     const float* __restrict__ trans,
                                                     float* __restrict__ out) {
    const int tid = threadIdx.x;     // 0..63
    const int q = tid >> 4;          // from-chunk 0..3 (from = 3q..3q+2)
    const int to = tid & 15;         // tag column (valid < 12)
    const int toc = (to < 12) ? to : 11;
    __shared__ float fbuf[256 * 12];
    __shared__ unsigned char bp[4096 * 12];

    const float trf0 = trans[(3 * q + 0) * 12 + toc];
    const float trf1 = trans[(3 * q + 1) * 12 + toc];
    const float trf2 = trans[(3 * q + 2) * 12 + toc];
    const float tstop = (tid < 12) ? trans[tid * 12 + STOP_TAG] : 0.f;
    float alpha = (tid == START_TAG) ? 0.f : NEG_VAL;  // meaningful lanes 0..11

    for (int ck = 0; ck < 16; ++ck) {
        __syncthreads();
        for (int i = tid; i < 3072; i += 64) fbuf[i] = feats[ck * 3072 + i];
        __syncthreads();
        for (int tt = 0; tt < 256; ++tt) {
            float feat = fbuf[tt * 12 + toc];
            float af0 = __shfl(alpha, 3 * q + 0);
            float af1 = __shfl(alpha, 3 * q + 1);
            float af2 = __shfl(alpha, 3 * q + 2);
            float s0 = (af0 + feat) + trf0;
            float s1 = (af1 + feat) + trf1;
            float s2 = (af2 + feat) + trf2;
            float m = s0; int bi = 3 * q;
            if (s1 > m) { m = s1; bi = 3 * q + 1; }
            if (s2 > m) { m = s2; bi = 3 * q + 2; }
            float mo = __shfl_xor(m, 16);
            int io = __shfl_xor(bi, 16);
            if (!((m > mo) || (m == mo && bi < io))) { m = mo; bi = io; }
            mo = __shfl_xor(m, 32);
            io = __shfl_xor(bi, 32);
            if (!((m > mo) || (m == mo && bi < io))) { m = mo; bi = io; }
            float e = __expf(s0 - m) + __expf(s1 - m) + __expf(s2 - m);
            e += __shfl_xor(e, 16);
            e += __shfl_xor(e, 32);
            alpha = __logf(e) + m;
            if (q == 0 && to < 12)
                bp[(ck * 256 + tt) * 12 + to] = (unsigned char)bi;
        }
    }
    __syncthreads();
    if (tid < 12) {
        float fin = alpha + tstop;
        float m = -INFINITY;
        int bl = 0;
        #pragma unroll
        for (int f = 0; f < 12; ++f) {
            float vf = __shfl(fin, f);
            if (vf > m) { m = vf; bl = f; }
        }
        float sum = 0.f;
        #pragma unroll
        for (int f = 0; f < 12; ++f) {
            float vf = __shfl(fin, f);
            sum += __expf(vf - m);
        }
        float score = __logf(sum) + m;
        if (tid == 0) {
            out[0] = score;            // output 0: score
            out[4096] = (float)bl;     // path[4095]
        }
        int cur = bl;
        for (int tt = 4095; tt >= 1; --tt) {
            int bv = (int)bp[tt * 12 + tid];
            cur = __shfl(bv, cur);     // path[tt-1] = bp[tt][path[tt]]
            if (tid == 0) out[tt] = (float)cur;
        }
    }
}

// ---------------------------------------------------------------------------
extern "C" void kernel_launch(void* const* d_in, const int* in_sizes, int n_in,
                              void* d_out, int out_size, void* d_ws, size_t ws_size,
                              hipStream_t stream) {
    (void)in_sizes; (void)n_in; (void)out_size; (void)ws_size;
    const int* sentence = (const int*)d_in[0];
    const int* chars = (const int*)d_in[1];
    // d_in[2] (caps) is unused by the reference forward
    const float* cemb = (const float*)d_in[3];
    const float* cw = (const float*)d_in[4];
    const float* cb = (const float*)d_in[5];
    const float* wemb = (const float*)d_in[6];
    const float* w_ih_f = (const float*)d_in[7];
    const float* w_hh_f = (const float*)d_in[8];
    const float* b_ih_f = (const float*)d_in[9];
    const float* b_hh_f = (const float*)d_in[10];
    const float* w_ih_b = (const float*)d_in[11];
    const float* w_hh_b = (const float*)d_in[12];
    const float* b_ih_b = (const float*)d_in[13];
    const float* b_hh_b = (const float*)d_in[14];
    const float* wtag = (const float*)d_in[15];
    const float* btag = (const float*)d_in[16];
    const float* trans = (const float*)d_in[17];

    float* ws = (float*)d_ws;
    unsigned short* emb_bf = (unsigned short*)(ws + OF_EMB);
    unsigned short* w_bf = (unsigned short*)(ws + OF_W);
    float* bias = ws + OF_BIAS;
    float* pre = ws + OF_PRE;
    float* hf = ws + OF_HF;
    float* hb = ws + OF_HB;
    float* feats = ws + OF_FEAT;

    // sentinel-fill h buffers, then zero the two initial-state slots
    (void)hipMemsetAsync(hf, 0xFF, 4097UL * 1024UL * 4UL, stream);
    (void)hipMemsetAsync(hb, 0xFF, 4097UL * 1024UL * 4UL, stream);
    (void)hipMemsetAsync(hf, 0x00, 1024UL * 4UL, stream);                    // hf slot 0
    (void)hipMemsetAsync(hb + 4096UL * 1024UL, 0x00, 1024UL * 4UL, stream);  // hb slot T

    hipLaunchKernelGGL(prep_w_kernel, dim3(8192), dim3(256), 0, stream,
                       w_ih_f, w_ih_b, b_ih_f, b_hh_f, b_ih_b, b_hh_b, w_bf, bias);
    hipLaunchKernelGGL(charcnn_kernel, dim3(4096), dim3(256), 0, stream,
                       sentence, chars, cemb, cw, cb, wemb, emb_bf);
    hipLaunchKernelGGL(sgemm_kernel, dim3(64, 32), dim3(256), 0, stream,
                       emb_bf, w_bf, bias, pre);
    hipLaunchKernelGGL(lstm_kernel, dim3(128), dim3(512), 0, stream,
                       w_hh_f, w_hh_b, pre, hf, hb);
    hipLaunchKernelGGL(tagproj_kernel, dim3(4096), dim3(192), 0, stream,
                       hf, hb, wtag, btag, feats);
    hipLaunchKernelGGL(viterbi_kernel, dim3(1), dim3(64), 0, stream,
                       feats, trans, (float*)d_out);
}